// Round 13
// baseline (100.948 us; speedup 1.0000x reference)
//
#include <hip/hip_runtime.h>
#include <stdint.h>

#define UNITS  4096
#define RPB    8          // consecutive rows per block; 16384 -> 2048 blocks = 8/CU, 1 generation
#define SEG    96         // per-wave list segment; wave window count 60.5 +- 7.55 -> +4.8 sigma
#define CAP    (4 * SEG)  // 384
#define NSLOT  6          // CAP/64
#define LOF    0.44f      // theta ~= 0.5244 +- 0.0206 ; [LO,HI) = +-4.1 sigma
#define HIF    0.61f
#define SELBITS 22        // bits(0.61f)-bits(0.44f) = 0x3AE148 < 2^22

typedef float v4f __attribute__((ext_vector_type(4)));

// LDS-only barrier (no vmcnt drain -> DMA prefetch + nt stores stay in flight)
__device__ __forceinline__ void lds_barrier() {
    asm volatile("s_waitcnt lgkmcnt(0)" ::: "memory");
    __builtin_amdgcn_s_barrier();
}
__device__ __forceinline__ uint32_t flipu(uint32_t b) {
    return b ^ (uint32_t)(((int32_t)b >> 31) | (int32_t)0x80000000);
}
__device__ __forceinline__ uint32_t mbcnt64(uint64_t m) {
    return __builtin_amdgcn_mbcnt_hi((uint32_t)(m >> 32),
           __builtin_amdgcn_mbcnt_lo((uint32_t)m, 0u));
}
// non-temporal 16B store (write-once output: don't pollute L2/L3)
__device__ __forceinline__ void nt_store4(float* p, float a, float b, float c, float d) {
    v4f v = {a, b, c, d};
    __builtin_nontemporal_store(v, (v4f*)p);
}
// async global->LDS, 16B/lane; LDS dst = wave-uniform base + lane*16
__device__ __forceinline__ void dma16(const float* g, float* l) {
    __builtin_amdgcn_global_load_lds(
        (const __attribute__((address_space(1))) void*)g,
        (__attribute__((address_space(3))) void*)l, 16, 0, 0);
}

// One block (256 threads), RPB consecutive rows. Per row: fused window
// ballots + per-wave-segment scatter (no atomics), ONE barrier, 4-wave
// redundant 2-bit/round ballot radix select over rebased 22-bit keys,
// nt mask-store from registers. Next row streams into LDS via DMA during
// select/store (regalloc-immune). Lists double-buffered -> still 1 barrier.
// Bracket+overflow verified per row; misses take the exact 32-bit fallback.
__global__ __launch_bounds__(256, 8) void ksparse_select_kernel(
        const float* __restrict__ X, float* __restrict__ out,
        int kidx, int rpb) {
    __shared__ float    buf[UNITS];        // 16 KiB DMA target (next row)
    __shared__ uint32_t list[2][CAP];      // 3 KiB, double-buffered, per-wave segs
    __shared__ uint32_t wnb[2][4];         // per-wave count below LO
    __shared__ uint32_t wc[2][4];          // per-wave window count
    __shared__ uint32_t fbc[4];            // fallback per-wave counts

    const int t    = threadIdx.x;
    const int w    = t >> 6;
    const int lane = t & 63;

    const float* Xb = X   + (size_t)blockIdx.x * rpb * UNITS;
    float*       Ob = out + (size_t)blockIdx.x * rpb * UNITS;

    // row 0 straight to registers
    float f[16];
    {
        const float4* Xv = reinterpret_cast<const float4*>(Xb);
#pragma unroll
        for (int j = 0; j < 4; ++j) {
            float4 v = Xv[j * 256 + t];
            f[4*j] = v.x; f[4*j+1] = v.y; f[4*j+2] = v.z; f[4*j+3] = v.w;
        }
    }
    // DMA prefetch row 1 (no dst registers -> nothing to sink/spill)
    if (rpb > 1) {
        const float* g = Xb + UNITS;
        const int base = (w << 6);
#pragma unroll
        for (int j = 0; j < 4; ++j) dma16(g + 4*(j*256+t), buf + 4*(j*256+base));
    }

    const uint32_t k   = (uint32_t)kidx;
    const uint32_t LOu = __float_as_uint(LOF);

#pragma unroll 1
    for (int r = 0;; ++r) {
        const int pb = r & 1;

        // fused window-count + segment scatter (single pass, no atomics)
        uint32_t nbw = 0, pfx = 0;
#pragma unroll
        for (int e = 0; e < 16; ++e) {
            const bool lo = f[e] < LOF;
            const bool hi = f[e] < HIF;
            const uint64_t mlo  = __ballot(lo);
            const uint64_t mwin = __ballot(hi && !lo);
            nbw += (uint32_t)__popcll(mlo);
            if (hi && !lo) {
                const uint32_t off = pfx + mbcnt64(mwin);
                if (off < SEG) list[pb][SEG * w + off] = __float_as_uint(f[e]) - LOu;
            }
            pfx += (uint32_t)__popcll(mwin);
        }
        if (lane == 0) { wnb[pb][w] = nbw; wc[pb][w] = pfx; }

        lds_barrier();  // list/wnb/wc of buffer pb visible (ONLY fast-path barrier)

        const uint32_t c0 = wc[pb][0], c1 = wc[pb][1], c2 = wc[pb][2], c3 = wc[pb][3];
        const uint32_t c  = c0 + c1 + c2 + c3;
        const uint32_t cb = wnb[pb][0] + wnb[pb][1] + wnb[pb][2] + wnb[pb][3];
        const uint32_t mx = max(max(c0, c1), max(c2, c3));

        float* Or = Ob + (size_t)r * UNITS;

        if (cb <= k && k < cb + c && mx <= SEG) {   // block-uniform bracket check
            const uint32_t rr = k - cb;

            // distributed list load, static (seg, off) map, sentinel-padded
            uint32_t sv[NSLOT];
            {
                const bool loh = lane < 32;
                uint32_t segi[NSLOT], offi[NSLOT];
                segi[0] = 0;             offi[0] = lane;
                segi[1] = loh ? 0 : 1;   offi[1] = loh ? 64 + lane : lane - 32;
                segi[2] = 1;             offi[2] = 32 + lane;
                segi[3] = 2;             offi[3] = lane;
                segi[4] = loh ? 2 : 3;   offi[4] = loh ? 64 + lane : lane - 32;
                segi[5] = 3;             offi[5] = 32 + lane;
#pragma unroll
                for (int i = 0; i < NSLOT; ++i)
                    sv[i] = (offi[i] < wc[pb][segi[i]]) ? list[pb][SEG * segi[i] + offi[i]]
                                                        : 0xFFFFFFFFu;
            }

            // MSB-first ballot radix select, 2 bits per round (11 rounds)
            uint32_t p = 0;
#pragma unroll
            for (int rb = SELBITS - 2; rb >= 0; rb -= 2) {
                const uint32_t m1 = p | (1u << rb);
                const uint32_t m2 = p | (2u << rb);
                const uint32_t m3 = p | (3u << rb);
                uint32_t n1 = 0, n2 = 0, n3 = 0;
#pragma unroll
                for (int i = 0; i < NSLOT; ++i) {
                    n1 += (uint32_t)__popcll(__ballot(sv[i] < m1));
                    n2 += (uint32_t)__popcll(__ballot(sv[i] < m2));
                    n3 += (uint32_t)__popcll(__ballot(sv[i] < m3));
                }
                if (n3 <= rr)      p = m3;   // wave-uniform
                else if (n2 <= rr) p = m2;
                else if (n1 <= rr) p = m1;
            }
            const float th = __uint_as_float(LOu + p);  // exact bits of theta

#pragma unroll
            for (int j = 0; j < 4; ++j) {
                nt_store4(Or + 4 * (j * 256 + t),
                          (f[4*j]   >= th) ? f[4*j]   : 0.0f,
                          (f[4*j+1] >= th) ? f[4*j+1] : 0.0f,
                          (f[4*j+2] >= th) ? f[4*j+2] : 0.0f,
                          (f[4*j+3] >= th) ? f[4*j+3] : 0.0f);
            }
        } else {
            // exact block-wide fallback (<1 row/dataset): 32-bit MSB bit-search
            uint32_t p = 0;
#pragma unroll 1
            for (int b = 31; b >= 0; --b) {
                const uint32_t mid = p | (1u << b);
                uint32_t cw = 0;
#pragma unroll
                for (int e = 0; e < 16; ++e)
                    cw += (uint32_t)__popcll(__ballot(flipu(__float_as_uint(f[e])) < mid));
                if (lane == 0) fbc[w] = cw;
                lds_barrier();
                const uint32_t cm = fbc[0] + fbc[1] + fbc[2] + fbc[3];
                if (cm <= k) p = mid;   // block-uniform
                lds_barrier();          // fbc consumed before next overwrite
            }
#pragma unroll
            for (int j = 0; j < 4; ++j) {
                nt_store4(Or + 4 * (j * 256 + t),
                          (flipu(__float_as_uint(f[4*j]))   >= p) ? f[4*j]   : 0.0f,
                          (flipu(__float_as_uint(f[4*j+1])) >= p) ? f[4*j+1] : 0.0f,
                          (flipu(__float_as_uint(f[4*j+2])) >= p) ? f[4*j+2] : 0.0f,
                          (flipu(__float_as_uint(f[4*j+3])) >= p) ? f[4*j+3] : 0.0f);
            }
        }

        if (r + 1 >= rpb) break;

        // consume prefetched row r+1: my wave's VMEM order is
        // [DMA row r+1 (4, older)] [nt stores row r (4, newest)];
        // vmcnt retires in order, so <=4 outstanding => DMAs landed.
        asm volatile("s_waitcnt vmcnt(4)" ::: "memory");
        __builtin_amdgcn_sched_barrier(0);
        {
            const float4* bv = reinterpret_cast<const float4*>(buf);
            float4 v[4];
#pragma unroll
            for (int j = 0; j < 4; ++j) v[j] = bv[j * 256 + t];   // own lane's bytes
            asm volatile("s_waitcnt lgkmcnt(0)" ::: "memory");    // buf reusable
            __builtin_amdgcn_sched_barrier(0);
            if (r + 2 < rpb) {   // prefetch row r+2 over the freed buffer
                const float* g = Xb + (size_t)(r + 2) * UNITS;
                const int base = (w << 6);
#pragma unroll
                for (int j = 0; j < 4; ++j) dma16(g + 4*(j*256+t), buf + 4*(j*256+base));
            }
#pragma unroll
            for (int j = 0; j < 4; ++j) {
                f[4*j] = v[j].x; f[4*j+1] = v[j].y; f[4*j+2] = v[j].z; f[4*j+3] = v[j].w;
            }
        }
    }
}

extern "C" void kernel_launch(void* const* d_in, const int* in_sizes, int n_in,
                              void* d_out, int out_size, void* d_ws, size_t ws_size,
                              hipStream_t stream) {
    const float* X = (const float*)d_in[0];
    float* out = (float*)d_out;
    const int rows = in_sizes[0] / UNITS;
    const int kidx = (int)(0.7 * UNITS);  // 2867
    const int rpb = (rows % RPB == 0) ? RPB : 1;
    const int nblocks = rows / rpb;
    ksparse_select_kernel<<<nblocks, 256, 0, stream>>>(X, out, kidx, rpb);
}